// Round 3
// baseline (1332.279 us; speedup 1.0000x reference)
//
#include <hip/hip_runtime.h>

#define NB 100000
#define NG 20000
#define EL 1000000
#define EX 200000
#define NSEG (2 * NB + NG)   // concatenated CSR rows: [line->bus | g2b->bus | b2g->gen]

static __device__ __forceinline__ int uni(int x) { return __builtin_amdgcn_readfirstlane(x); }

// ---- int degree count: deg[dst[i]] += 1 ----
__global__ void counti_kernel(const int* __restrict__ dst, int* __restrict__ deg, int E) {
    int i = blockIdx.x * blockDim.x + threadIdx.x;
    if (i < E) atomicAdd(&deg[dst[i]], 1);
}

// ---- single-block exclusive scan of deg[0..n) -> off[0..n], plus cursor copy ----
__global__ __launch_bounds__(1024) void scan_kernel(const int* __restrict__ deg,
                                                    int* __restrict__ off,
                                                    int* __restrict__ cursor, int n) {
    __shared__ int ls[1024];
    const int t = threadIdx.x;
    const int chunk = (n + 1023) >> 10;
    const int b0 = t * chunk;
    const int b1 = min(b0 + chunk, n);
    int s = 0;
    for (int i = b0; i < b1; ++i) s += deg[i];
    ls[t] = s;
    __syncthreads();
    for (int d = 1; d < 1024; d <<= 1) {
        int v = (t >= d) ? ls[t - d] : 0;
        __syncthreads();
        ls[t] += v;
        __syncthreads();
    }
    int run = (t == 0) ? 0 : ls[t - 1];
    for (int i = b0; i < b1; ++i) {
        off[i] = run; cursor[i] = run; run += deg[i];
    }
    if (t == 1023) off[n] = run;
}

// ---- CSR fill: elist[cursor[base+dst]++] = src ----
__global__ void fill_kernel(const int* __restrict__ src, const int* __restrict__ dst,
                            int* __restrict__ cursor, int* __restrict__ elist, int E, int base) {
    int i = blockIdx.x * blockDim.x + threadIdx.x;
    if (i < E) {
        int pos = atomicAdd(&cursor[base + dst[i]], 1);
        elist[pos] = src[i];
    }
}

// ---- bus-node aggregation: Aline[b] = mean hb[src in line(b)], Ag2b[b] = mean hg[src in g2b(b)] ----
__global__ __launch_bounds__(256) void aggr_bus_kernel(
    const float* __restrict__ hb, const float* __restrict__ hg,
    const int* __restrict__ off, const int* __restrict__ elist,
    float* __restrict__ Aline, float* __restrict__ Ag2b)
{
    const int lane = threadIdx.x & 63;
    int b = uni(blockIdx.x * 4 + (threadIdx.x >> 6));
    if (b >= NB) return;
    int s0 = off[b], e0 = off[b + 1];
    float s = 0.f;
    for (int e = s0; e < e0; ++e) s += hb[(size_t)elist[e] * 64 + lane];
    Aline[(size_t)b * 64 + lane] = s / fmaxf((float)(e0 - s0), 1.f);
    int s1 = off[NB + b], e1 = off[NB + b + 1];
    float g = 0.f;
    for (int e = s1; e < e1; ++e) g += hg[(size_t)elist[e] * 64 + lane];
    Ag2b[(size_t)b * 64 + lane] = g / fmaxf((float)(e1 - s1), 1.f);
}

// ---- gen-node aggregation: Ab2g[g] = mean hb[src in b2g(g)] ----
__global__ __launch_bounds__(256) void aggr_gen_kernel(
    const float* __restrict__ hb, const int* __restrict__ off, const int* __restrict__ elist,
    float* __restrict__ Ab2g)
{
    const int lane = threadIdx.x & 63;
    int g = uni(blockIdx.x * 4 + (threadIdx.x >> 6));
    if (g >= NG) return;
    int s0 = off[2 * NB + g], e0 = off[2 * NB + g + 1];
    float s = 0.f;
    for (int e = s0; e < e0; ++e) s += hb[(size_t)elist[e] * 64 + lane];
    Ab2g[(size_t)g * 64 + lane] = s / fmaxf((float)(e0 - s0), 1.f);
}

// ---- bus combine: out = relu(h@Wsb + Al@Wl + Ag@Wg + b). out may alias Al (row-to-row). ----
__global__ __launch_bounds__(256) void combine_bus_kernel(
    const float* __restrict__ h, const float* Al, const float* Ag,
    const float* __restrict__ Wsb, const float* __restrict__ Wl, const float* __restrict__ Wg,
    const float* __restrict__ bias, float* out, int n)
{
    const int lane = threadIdx.x & 63;
    int row = uni(blockIdx.x * 4 + (threadIdx.x >> 6));
    float wsb[64], wl[64], wg[64];
#pragma unroll
    for (int k = 0; k < 64; ++k) {
        wsb[k] = Wsb[k * 64 + lane];
        wl[k]  = Wl[k * 64 + lane];
        wg[k]  = Wg[k * 64 + lane];
    }
    if (row >= n) return;
    const float bv = bias[lane];
    const float* hr = h + (size_t)row * 64;
    const float* ar = Al + (size_t)row * 64;
    const float* gr = Ag + (size_t)row * 64;
    float a1 = 0.f, a2 = 0.f, a3 = 0.f;
#pragma unroll
    for (int k = 0; k < 64; ++k) {
        a1 += hr[k] * wsb[k];
        a2 += ar[k] * wl[k];
        a3 += gr[k] * wg[k];
    }
    out[(size_t)row * 64 + lane] = fmaxf(a1 + a2 + a3 + bv, 0.f);
}

// ---- gen combine: out = relu(h@Wsg + A@Wm + b). out may alias A (row-to-row). ----
__global__ __launch_bounds__(256) void combine_gen_kernel(
    const float* __restrict__ h, const float* A,
    const float* __restrict__ Wsg, const float* __restrict__ Wm,
    const float* __restrict__ bias, float* out, int n)
{
    const int lane = threadIdx.x & 63;
    int row = uni(blockIdx.x * 4 + (threadIdx.x >> 6));
    float ws[64], wm[64];
#pragma unroll
    for (int k = 0; k < 64; ++k) {
        ws[k] = Wsg[k * 64 + lane];
        wm[k] = Wm[k * 64 + lane];
    }
    if (row >= n) return;
    const float* hr = h + (size_t)row * 64;
    const float* ar = A + (size_t)row * 64;
    float a1 = 0.f, a2 = 0.f;
#pragma unroll
    for (int k = 0; k < 64; ++k) {
        a1 += hr[k] * ws[k];
        a2 += ar[k] * wm[k];
    }
    out[(size_t)row * 64 + lane] = fmaxf(a1 + a2 + bias[lane], 0.f);
}

// ---- column-sum pool ----
__global__ __launch_bounds__(256) void pool_kernel(
    const float* __restrict__ h, int n, float* __restrict__ pool)
{
    int lane = threadIdx.x & 63;
    int w = threadIdx.x >> 6;
    float s = 0.f;
    for (int row = blockIdx.x * 4 + w; row < n; row += gridDim.x * 4)
        s += h[(size_t)row * 64 + lane];
    __shared__ float red[256];
    red[threadIdx.x] = s;
    __syncthreads();
    if (threadIdx.x < 64) {
        float t = red[threadIdx.x] + red[threadIdx.x + 64] + red[threadIdx.x + 128] + red[threadIdx.x + 192];
        atomicAdd(&pool[lane], t);
    }
}

// ---- head: out = relu(g @ Wh + bh) @ Wo + bo ----
__global__ void head_kernel(const float* __restrict__ pool,
                            const float* __restrict__ Wh, const float* __restrict__ bh,
                            const float* __restrict__ Wo, const float* __restrict__ bo,
                            float* __restrict__ out)
{
    __shared__ float g[128];
    __shared__ float hid[64];
    int t = threadIdx.x;  // 128 threads
    g[t] = pool[t];
    __syncthreads();
    if (t < 64) {
        float a = bh[t];
        for (int i = 0; i < 128; ++i) a += g[i] * Wh[i * 64 + t];
        hid[t] = fmaxf(a, 0.f);
    }
    __syncthreads();
    if (t < 16) {
        float a = bo[t];
        for (int j = 0; j < 64; ++j) a += hid[j] * Wo[j * 16 + t];
        out[t] = a;
    }
}

extern "C" void kernel_launch(void* const* d_in, const int* in_sizes, int n_in,
                              void* d_out, int out_size, void* d_ws, size_t ws_size,
                              hipStream_t stream)
{
    const float* x_bus   = (const float*)d_in[0];
    const float* x_gen   = (const float*)d_in[1];
    const int* line_src  = (const int*)d_in[2];
    const int* line_dst  = (const int*)d_in[3];
    const int* g2b_src   = (const int*)d_in[4];
    const int* g2b_dst   = (const int*)d_in[5];
    const int* b2g_src   = (const int*)d_in[6];
    const int* b2g_dst   = (const int*)d_in[7];
    const float* Wsb[2]  = {(const float*)d_in[8],  (const float*)d_in[15]};
    const float* Wsg[2]  = {(const float*)d_in[9],  (const float*)d_in[16]};
    const float* Wl[2]   = {(const float*)d_in[10], (const float*)d_in[17]};
    const float* Wg2b[2] = {(const float*)d_in[11], (const float*)d_in[18]};
    const float* Wb2g[2] = {(const float*)d_in[12], (const float*)d_in[19]};
    const float* bsb[2]  = {(const float*)d_in[13], (const float*)d_in[20]};
    const float* bsg[2]  = {(const float*)d_in[14], (const float*)d_in[21]};
    const float* Wh = (const float*)d_in[22];
    const float* bh = (const float*)d_in[23];
    const float* Wo = (const float*)d_in[24];
    const float* bo = (const float*)d_in[25];
    (void)in_sizes; (void)n_in; (void)out_size; (void)ws_size;

    char* wsB = (char*)d_ws;
    size_t o = 0;
    auto alloc_f = [&](size_t nelem) { float* p = (float*)(wsB + o); o += nelem * sizeof(float); return p; };
    auto alloc_i = [&](size_t nelem) { int*   p = (int*)  (wsB + o); o += nelem * sizeof(int);   return p; };

    float* H1b   = alloc_f((size_t)NB * 64);   // layer-0 bus output
    float* H1g   = alloc_f((size_t)NG * 64);   // layer-0 gen output
    float* Aline = alloc_f((size_t)NB * 64);   // also final hb (layer-1 combine writes here)
    float* Ag2b  = alloc_f((size_t)NB * 64);
    float* Ab2g  = alloc_f((size_t)NG * 64);   // also final hg
    int*   elist = alloc_i(EL + 2 * EX);
    int*   deg   = alloc_i(NSEG);
    int*   off   = alloc_i(NSEG + 1);
    int*   cur   = alloc_i(NSEG);
    float* pool  = alloc_f(128);

    // ---- CSR build (graph is identical both layers; built once per call) ----
    hipMemsetAsync(deg, 0, NSEG * sizeof(int), stream);
    hipMemsetAsync(pool, 0, 128 * sizeof(float), stream);
    counti_kernel<<<(EL + 255) / 256, 256, 0, stream>>>(line_dst, deg, EL);
    counti_kernel<<<(EX + 255) / 256, 256, 0, stream>>>(g2b_dst, deg + NB, EX);
    counti_kernel<<<(EX + 255) / 256, 256, 0, stream>>>(b2g_dst, deg + 2 * NB, EX);
    scan_kernel<<<1, 1024, 0, stream>>>(deg, off, cur, NSEG);
    fill_kernel<<<(EL + 255) / 256, 256, 0, stream>>>(line_src, line_dst, cur, elist, EL, 0);
    fill_kernel<<<(EX + 255) / 256, 256, 0, stream>>>(g2b_src, g2b_dst, cur, elist, EX, NB);
    fill_kernel<<<(EX + 255) / 256, 256, 0, stream>>>(b2g_src, b2g_dst, cur, elist, EX, 2 * NB);

    const int gbB = (NB + 3) / 4, gbG = (NG + 3) / 4;

    // ---- layer 0 ----
    aggr_bus_kernel<<<gbB, 256, 0, stream>>>(x_bus, x_gen, off, elist, Aline, Ag2b);
    aggr_gen_kernel<<<gbG, 256, 0, stream>>>(x_bus, off, elist, Ab2g);
    combine_bus_kernel<<<gbB, 256, 0, stream>>>(x_bus, Aline, Ag2b, Wsb[0], Wl[0], Wg2b[0], bsb[0], H1b, NB);
    combine_gen_kernel<<<gbG, 256, 0, stream>>>(x_gen, Ab2g, Wsg[0], Wb2g[0], bsg[0], H1g, NG);

    // ---- layer 1 (combine outputs alias A buffers row-to-row) ----
    aggr_bus_kernel<<<gbB, 256, 0, stream>>>(H1b, H1g, off, elist, Aline, Ag2b);
    aggr_gen_kernel<<<gbG, 256, 0, stream>>>(H1b, off, elist, Ab2g);
    combine_bus_kernel<<<gbB, 256, 0, stream>>>(H1b, Aline, Ag2b, Wsb[1], Wl[1], Wg2b[1], bsb[1], Aline, NB);
    combine_gen_kernel<<<gbG, 256, 0, stream>>>(H1g, Ab2g, Wsg[1], Wb2g[1], bsg[1], Ab2g, NG);

    // ---- pool + head ----
    pool_kernel<<<512, 256, 0, stream>>>(Aline, NB, pool);
    pool_kernel<<<512, 256, 0, stream>>>(Ab2g, NG, pool + 64);
    head_kernel<<<1, 128, 0, stream>>>(pool, Wh, bh, Wo, bo, (float*)d_out);
}

// Round 4
// 828.141 us; speedup vs baseline: 1.6088x; 1.6088x over previous
//
#include <hip/hip_runtime.h>

#define NB 100000
#define NG 20000
#define EL 1000000
#define EX 200000
#define NSEG (2 * NB + NG)   // concatenated CSR rows: [line->bus | g2b->bus | b2g->gen]
#define TILE 2048
#define NTILES ((NSEG + TILE - 1) / TILE)   // 108 (must be <= 256)

static __device__ __forceinline__ int uni(int x) { return __builtin_amdgcn_readfirstlane(x); }

// ---- int degree count: deg[dst[i]] += 1 ----
__global__ void counti_kernel(const int* __restrict__ dst, int* __restrict__ deg, int E) {
    int i = blockIdx.x * blockDim.x + threadIdx.x;
    if (i < E) atomicAdd(&deg[dst[i]], 1);
}

// ---- hierarchical scan, stage 1: per-tile sums (coalesced) ----
__global__ __launch_bounds__(256) void scan_part_kernel(const int* __restrict__ deg,
                                                        int* __restrict__ partial, int n) {
    __shared__ int ls[256];
    const int t = threadIdx.x;
    const int base = blockIdx.x * TILE;
    int s = 0;
    for (int i = t; i < TILE; i += 256) {
        int idx = base + i;
        s += (idx < n) ? deg[idx] : 0;
    }
    ls[t] = s;
    __syncthreads();
    for (int d = 128; d > 0; d >>= 1) {
        if (t < d) ls[t] += ls[t + d];
        __syncthreads();
    }
    if (t == 0) partial[blockIdx.x] = ls[0];
}

// ---- stage 2: single-block exclusive scan of partials; writes off[n]=total ----
__global__ __launch_bounds__(256) void scan_top_kernel(int* __restrict__ partial,
                                                       int* __restrict__ off, int nparts, int n) {
    __shared__ int ls[256];
    const int t = threadIdx.x;
    ls[t] = (t < nparts) ? partial[t] : 0;
    __syncthreads();
    for (int d = 1; d < 256; d <<= 1) {
        int x = (t >= d) ? ls[t - d] : 0;
        __syncthreads();
        ls[t] += x;
        __syncthreads();
    }
    if (t < nparts) partial[t] = (t == 0) ? 0 : ls[t - 1];
    if (t == 255) off[n] = ls[255];
}

// ---- stage 3: per-tile exclusive scan + global base; writes off and cursor ----
__global__ __launch_bounds__(256) void scan_write_kernel(const int* __restrict__ deg,
                                                         const int* __restrict__ partial,
                                                         int* __restrict__ off,
                                                         int* __restrict__ cur, int n) {
    __shared__ int ls[256];
    const int t = threadIdx.x;
    const int b0 = blockIdx.x * TILE + t * 8;
    int local[8];
    int s = 0;
#pragma unroll
    for (int j = 0; j < 8; ++j) {
        int idx = b0 + j;
        local[j] = (idx < n) ? deg[idx] : 0;
        s += local[j];
    }
    ls[t] = s;
    __syncthreads();
    for (int d = 1; d < 256; d <<= 1) {
        int x = (t >= d) ? ls[t - d] : 0;
        __syncthreads();
        ls[t] += x;
        __syncthreads();
    }
    int run = partial[blockIdx.x] + ((t == 0) ? 0 : ls[t - 1]);
#pragma unroll
    for (int j = 0; j < 8; ++j) {
        int idx = b0 + j;
        if (idx < n) { off[idx] = run; cur[idx] = run; run += local[j]; }
    }
}

// ---- CSR fill: elist[cursor[base+dst]++] = src ----
__global__ void fill_kernel(const int* __restrict__ src, const int* __restrict__ dst,
                            int* __restrict__ cursor, int* __restrict__ elist, int E, int base) {
    int i = blockIdx.x * blockDim.x + threadIdx.x;
    if (i < E) {
        int pos = atomicAdd(&cursor[base + dst[i]], 1);
        elist[pos] = src[i];
    }
}

// ---- bus-node aggregation: Aline[b] = mean hb[src in line(b)], Ag2b[b] = mean hg[src in g2b(b)] ----
__global__ __launch_bounds__(256) void aggr_bus_kernel(
    const float* __restrict__ hb, const float* __restrict__ hg,
    const int* __restrict__ off, const int* __restrict__ elist,
    float* __restrict__ Aline, float* __restrict__ Ag2b)
{
    const int lane = threadIdx.x & 63;
    int b = uni(blockIdx.x * 4 + (threadIdx.x >> 6));
    if (b >= NB) return;
    int s0 = off[b], e0 = off[b + 1];
    float s = 0.f;
    for (int e = s0; e < e0; ++e) s += hb[(size_t)elist[e] * 64 + lane];
    Aline[(size_t)b * 64 + lane] = s / fmaxf((float)(e0 - s0), 1.f);
    int s1 = off[NB + b], e1 = off[NB + b + 1];
    float g = 0.f;
    for (int e = s1; e < e1; ++e) g += hg[(size_t)elist[e] * 64 + lane];
    Ag2b[(size_t)b * 64 + lane] = g / fmaxf((float)(e1 - s1), 1.f);
}

// ---- gen-node aggregation: Ab2g[g] = mean hb[src in b2g(g)] ----
__global__ __launch_bounds__(256) void aggr_gen_kernel(
    const float* __restrict__ hb, const int* __restrict__ off, const int* __restrict__ elist,
    float* __restrict__ Ab2g)
{
    const int lane = threadIdx.x & 63;
    int g = uni(blockIdx.x * 4 + (threadIdx.x >> 6));
    if (g >= NG) return;
    int s0 = off[2 * NB + g], e0 = off[2 * NB + g + 1];
    float s = 0.f;
    for (int e = s0; e < e0; ++e) s += hb[(size_t)elist[e] * 64 + lane];
    Ab2g[(size_t)g * 64 + lane] = s / fmaxf((float)(e0 - s0), 1.f);
}

// ---- bus combine: out = relu(h@Wsb + Al@Wl + Ag@Wg + b). out may alias Al (row-to-row). ----
__global__ __launch_bounds__(256) void combine_bus_kernel(
    const float* __restrict__ h, const float* Al, const float* Ag,
    const float* __restrict__ Wsb, const float* __restrict__ Wl, const float* __restrict__ Wg,
    const float* __restrict__ bias, float* out, int n)
{
    const int lane = threadIdx.x & 63;
    int row = uni(blockIdx.x * 4 + (threadIdx.x >> 6));
    float wsb[64], wl[64], wg[64];
#pragma unroll
    for (int k = 0; k < 64; ++k) {
        wsb[k] = Wsb[k * 64 + lane];
        wl[k]  = Wl[k * 64 + lane];
        wg[k]  = Wg[k * 64 + lane];
    }
    if (row >= n) return;
    const float bv = bias[lane];
    const float* hr = h + (size_t)row * 64;
    const float* ar = Al + (size_t)row * 64;
    const float* gr = Ag + (size_t)row * 64;
    float a1 = 0.f, a2 = 0.f, a3 = 0.f;
#pragma unroll
    for (int k = 0; k < 64; ++k) {
        a1 += hr[k] * wsb[k];
        a2 += ar[k] * wl[k];
        a3 += gr[k] * wg[k];
    }
    out[(size_t)row * 64 + lane] = fmaxf(a1 + a2 + a3 + bv, 0.f);
}

// ---- gen combine: out = relu(h@Wsg + A@Wm + b). out may alias A (row-to-row). ----
__global__ __launch_bounds__(256) void combine_gen_kernel(
    const float* __restrict__ h, const float* A,
    const float* __restrict__ Wsg, const float* __restrict__ Wm,
    const float* __restrict__ bias, float* out, int n)
{
    const int lane = threadIdx.x & 63;
    int row = uni(blockIdx.x * 4 + (threadIdx.x >> 6));
    float ws[64], wm[64];
#pragma unroll
    for (int k = 0; k < 64; ++k) {
        ws[k] = Wsg[k * 64 + lane];
        wm[k] = Wm[k * 64 + lane];
    }
    if (row >= n) return;
    const float* hr = h + (size_t)row * 64;
    const float* ar = A + (size_t)row * 64;
    float a1 = 0.f, a2 = 0.f;
#pragma unroll
    for (int k = 0; k < 64; ++k) {
        a1 += hr[k] * ws[k];
        a2 += ar[k] * wm[k];
    }
    out[(size_t)row * 64 + lane] = fmaxf(a1 + a2 + bias[lane], 0.f);
}

// ---- column-sum pool ----
__global__ __launch_bounds__(256) void pool_kernel(
    const float* __restrict__ h, int n, float* __restrict__ pool)
{
    int lane = threadIdx.x & 63;
    int w = threadIdx.x >> 6;
    float s = 0.f;
    for (int row = blockIdx.x * 4 + w; row < n; row += gridDim.x * 4)
        s += h[(size_t)row * 64 + lane];
    __shared__ float red[256];
    red[threadIdx.x] = s;
    __syncthreads();
    if (threadIdx.x < 64) {
        float t = red[threadIdx.x] + red[threadIdx.x + 64] + red[threadIdx.x + 128] + red[threadIdx.x + 192];
        atomicAdd(&pool[lane], t);
    }
}

// ---- head: out = relu(g @ Wh + bh) @ Wo + bo ----
__global__ void head_kernel(const float* __restrict__ pool,
                            const float* __restrict__ Wh, const float* __restrict__ bh,
                            const float* __restrict__ Wo, const float* __restrict__ bo,
                            float* __restrict__ out)
{
    __shared__ float g[128];
    __shared__ float hid[64];
    int t = threadIdx.x;  // 128 threads
    g[t] = pool[t];
    __syncthreads();
    if (t < 64) {
        float a = bh[t];
        for (int i = 0; i < 128; ++i) a += g[i] * Wh[i * 64 + t];
        hid[t] = fmaxf(a, 0.f);
    }
    __syncthreads();
    if (t < 16) {
        float a = bo[t];
        for (int j = 0; j < 64; ++j) a += hid[j] * Wo[j * 16 + t];
        out[t] = a;
    }
}

extern "C" void kernel_launch(void* const* d_in, const int* in_sizes, int n_in,
                              void* d_out, int out_size, void* d_ws, size_t ws_size,
                              hipStream_t stream)
{
    const float* x_bus   = (const float*)d_in[0];
    const float* x_gen   = (const float*)d_in[1];
    const int* line_src  = (const int*)d_in[2];
    const int* line_dst  = (const int*)d_in[3];
    const int* g2b_src   = (const int*)d_in[4];
    const int* g2b_dst   = (const int*)d_in[5];
    const int* b2g_src   = (const int*)d_in[6];
    const int* b2g_dst   = (const int*)d_in[7];
    const float* Wsb[2]  = {(const float*)d_in[8],  (const float*)d_in[15]};
    const float* Wsg[2]  = {(const float*)d_in[9],  (const float*)d_in[16]};
    const float* Wl[2]   = {(const float*)d_in[10], (const float*)d_in[17]};
    const float* Wg2b[2] = {(const float*)d_in[11], (const float*)d_in[18]};
    const float* Wb2g[2] = {(const float*)d_in[12], (const float*)d_in[19]};
    const float* bsb[2]  = {(const float*)d_in[13], (const float*)d_in[20]};
    const float* bsg[2]  = {(const float*)d_in[14], (const float*)d_in[21]};
    const float* Wh = (const float*)d_in[22];
    const float* bh = (const float*)d_in[23];
    const float* Wo = (const float*)d_in[24];
    const float* bo = (const float*)d_in[25];
    (void)in_sizes; (void)n_in; (void)out_size; (void)ws_size;

    char* wsB = (char*)d_ws;
    size_t o = 0;
    auto alloc_f = [&](size_t nelem) { float* p = (float*)(wsB + o); o += nelem * sizeof(float); return p; };
    auto alloc_i = [&](size_t nelem) { int*   p = (int*)  (wsB + o); o += nelem * sizeof(int);   return p; };

    float* H1b   = alloc_f((size_t)NB * 64);   // layer-0 bus output
    float* H1g   = alloc_f((size_t)NG * 64);   // layer-0 gen output
    float* Aline = alloc_f((size_t)NB * 64);   // also final hb (layer-1 combine writes here)
    float* Ag2b  = alloc_f((size_t)NB * 64);
    float* Ab2g  = alloc_f((size_t)NG * 64);   // also final hg
    int*   elist = alloc_i(EL + 2 * EX);
    int*   deg   = alloc_i(NSEG);
    int*   off   = alloc_i(NSEG + 1);
    int*   cur   = alloc_i(NSEG);
    int*   part  = alloc_i(256);
    float* pool  = alloc_f(128);

    // ---- CSR build (graph is identical both layers; built once per call) ----
    hipMemsetAsync(deg, 0, NSEG * sizeof(int), stream);
    hipMemsetAsync(pool, 0, 128 * sizeof(float), stream);
    counti_kernel<<<(EL + 255) / 256, 256, 0, stream>>>(line_dst, deg, EL);
    counti_kernel<<<(EX + 255) / 256, 256, 0, stream>>>(g2b_dst, deg + NB, EX);
    counti_kernel<<<(EX + 255) / 256, 256, 0, stream>>>(b2g_dst, deg + 2 * NB, EX);
    scan_part_kernel<<<NTILES, 256, 0, stream>>>(deg, part, NSEG);
    scan_top_kernel<<<1, 256, 0, stream>>>(part, off, NTILES, NSEG);
    scan_write_kernel<<<NTILES, 256, 0, stream>>>(deg, part, off, cur, NSEG);
    fill_kernel<<<(EL + 255) / 256, 256, 0, stream>>>(line_src, line_dst, cur, elist, EL, 0);
    fill_kernel<<<(EX + 255) / 256, 256, 0, stream>>>(g2b_src, g2b_dst, cur, elist, EX, NB);
    fill_kernel<<<(EX + 255) / 256, 256, 0, stream>>>(b2g_src, b2g_dst, cur, elist, EX, 2 * NB);

    const int gbB = (NB + 3) / 4, gbG = (NG + 3) / 4;

    // ---- layer 0 ----
    aggr_bus_kernel<<<gbB, 256, 0, stream>>>(x_bus, x_gen, off, elist, Aline, Ag2b);
    aggr_gen_kernel<<<gbG, 256, 0, stream>>>(x_bus, off, elist, Ab2g);
    combine_bus_kernel<<<gbB, 256, 0, stream>>>(x_bus, Aline, Ag2b, Wsb[0], Wl[0], Wg2b[0], bsb[0], H1b, NB);
    combine_gen_kernel<<<gbG, 256, 0, stream>>>(x_gen, Ab2g, Wsg[0], Wb2g[0], bsg[0], H1g, NG);

    // ---- layer 1 (combine outputs alias A buffers row-to-row) ----
    aggr_bus_kernel<<<gbB, 256, 0, stream>>>(H1b, H1g, off, elist, Aline, Ag2b);
    aggr_gen_kernel<<<gbG, 256, 0, stream>>>(H1b, off, elist, Ab2g);
    combine_bus_kernel<<<gbB, 256, 0, stream>>>(H1b, Aline, Ag2b, Wsb[1], Wl[1], Wg2b[1], bsb[1], Aline, NB);
    combine_gen_kernel<<<gbG, 256, 0, stream>>>(H1g, Ab2g, Wsg[1], Wb2g[1], bsg[1], Ab2g, NG);

    // ---- pool + head ----
    pool_kernel<<<512, 256, 0, stream>>>(Aline, NB, pool);
    pool_kernel<<<512, 256, 0, stream>>>(Ab2g, NG, pool + 64);
    head_kernel<<<1, 128, 0, stream>>>(pool, Wh, bh, Wo, bo, (float*)d_out);
}

// Round 5
// 730.730 us; speedup vs baseline: 1.8232x; 1.1333x over previous
//
#include <hip/hip_runtime.h>

#define NB 100000
#define NG 20000
#define EL 1000000
#define EX 200000
#define NSEG (2 * NB + NG)   // concatenated CSR rows: [line->bus | g2b->bus | b2g->gen]
#define TILE 2048
#define NTILES ((NSEG + TILE - 1) / TILE)   // 108 (must be <= 256)

static __device__ __forceinline__ int uni(int x) { return __builtin_amdgcn_readfirstlane(x); }

// ---- int degree count: deg[dst[i]] += 1 ----
__global__ void counti_kernel(const int* __restrict__ dst, int* __restrict__ deg, int E) {
    int i = blockIdx.x * blockDim.x + threadIdx.x;
    if (i < E) atomicAdd(&deg[dst[i]], 1);
}

// ---- hierarchical scan, stage 1: per-tile sums (coalesced) ----
__global__ __launch_bounds__(256) void scan_part_kernel(const int* __restrict__ deg,
                                                        int* __restrict__ partial, int n) {
    __shared__ int ls[256];
    const int t = threadIdx.x;
    const int base = blockIdx.x * TILE;
    int s = 0;
    for (int i = t; i < TILE; i += 256) {
        int idx = base + i;
        s += (idx < n) ? deg[idx] : 0;
    }
    ls[t] = s;
    __syncthreads();
    for (int d = 128; d > 0; d >>= 1) {
        if (t < d) ls[t] += ls[t + d];
        __syncthreads();
    }
    if (t == 0) partial[blockIdx.x] = ls[0];
}

// ---- stage 2: single-block exclusive scan of partials; writes off[n]=total ----
__global__ __launch_bounds__(256) void scan_top_kernel(int* __restrict__ partial,
                                                       int* __restrict__ off, int nparts, int n) {
    __shared__ int ls[256];
    const int t = threadIdx.x;
    ls[t] = (t < nparts) ? partial[t] : 0;
    __syncthreads();
    for (int d = 1; d < 256; d <<= 1) {
        int x = (t >= d) ? ls[t - d] : 0;
        __syncthreads();
        ls[t] += x;
        __syncthreads();
    }
    if (t < nparts) partial[t] = (t == 0) ? 0 : ls[t - 1];
    if (t == 255) off[n] = ls[255];
}

// ---- stage 3: per-tile exclusive scan + global base; writes off and cursor ----
__global__ __launch_bounds__(256) void scan_write_kernel(const int* __restrict__ deg,
                                                         const int* __restrict__ partial,
                                                         int* __restrict__ off,
                                                         int* __restrict__ cur, int n) {
    __shared__ int ls[256];
    const int t = threadIdx.x;
    const int b0 = blockIdx.x * TILE + t * 8;
    int local[8];
    int s = 0;
#pragma unroll
    for (int j = 0; j < 8; ++j) {
        int idx = b0 + j;
        local[j] = (idx < n) ? deg[idx] : 0;
        s += local[j];
    }
    ls[t] = s;
    __syncthreads();
    for (int d = 1; d < 256; d <<= 1) {
        int x = (t >= d) ? ls[t - d] : 0;
        __syncthreads();
        ls[t] += x;
        __syncthreads();
    }
    int run = partial[blockIdx.x] + ((t == 0) ? 0 : ls[t - 1]);
#pragma unroll
    for (int j = 0; j < 8; ++j) {
        int idx = b0 + j;
        if (idx < n) { off[idx] = run; cur[idx] = run; run += local[j]; }
    }
}

// ---- CSR fill: elist[cursor[base+dst]++] = src ----
__global__ void fill_kernel(const int* __restrict__ src, const int* __restrict__ dst,
                            int* __restrict__ cursor, int* __restrict__ elist, int E, int base) {
    int i = blockIdx.x * blockDim.x + threadIdx.x;
    if (i < E) {
        int pos = atomicAdd(&cursor[base + dst[i]], 1);
        elist[pos] = src[i];
    }
}

// ---- mean over CSR segment with 4-wide load pipelining ----
static __device__ __forceinline__ float seg_mean(const float* __restrict__ h,
                                                 const int* __restrict__ elist,
                                                 int s0, int e0, int lane) {
    float s = 0.f;
    int e = s0;
    for (; e + 4 <= e0; e += 4) {
        int i0 = elist[e], i1 = elist[e + 1], i2 = elist[e + 2], i3 = elist[e + 3];
        float v0 = h[(size_t)i0 * 64 + lane];
        float v1 = h[(size_t)i1 * 64 + lane];
        float v2 = h[(size_t)i2 * 64 + lane];
        float v3 = h[(size_t)i3 * 64 + lane];
        s += v0 + v1 + v2 + v3;
    }
    for (; e < e0; ++e) s += h[(size_t)elist[e] * 64 + lane];
    return s / fmaxf((float)(e0 - s0), 1.f);
}

// ---- bus-node aggregation: Aline[b] = mean hb[src in line(b)], Ag2b[b] = mean hg[src in g2b(b)] ----
__global__ __launch_bounds__(256) void aggr_bus_kernel(
    const float* __restrict__ hb, const float* __restrict__ hg,
    const int* __restrict__ off, const int* __restrict__ elist,
    float* __restrict__ Aline, float* __restrict__ Ag2b)
{
    const int lane = threadIdx.x & 63;
    int b = uni(blockIdx.x * 4 + (threadIdx.x >> 6));
    if (b >= NB) return;
    Aline[(size_t)b * 64 + lane] = seg_mean(hb, elist, off[b], off[b + 1], lane);
    Ag2b[(size_t)b * 64 + lane]  = seg_mean(hg, elist, off[NB + b], off[NB + b + 1], lane);
}

// ---- gen-node aggregation: Ab2g[g] = mean hb[src in b2g(g)] ----
__global__ __launch_bounds__(256) void aggr_gen_kernel(
    const float* __restrict__ hb, const int* __restrict__ off, const int* __restrict__ elist,
    float* __restrict__ Ab2g)
{
    const int lane = threadIdx.x & 63;
    int g = uni(blockIdx.x * 4 + (threadIdx.x >> 6));
    if (g >= NG) return;
    Ab2g[(size_t)g * 64 + lane] = seg_mean(hb, elist, off[2 * NB + g], off[2 * NB + g + 1], lane);
}

// ---- bus combine: out = relu(h@Wsb + Al@Wl + Ag@Wg + b). Grid-stride: weights amortized
//      over ~24 rows/wave (one-row-per-wave made the compiler drop weight registers: R4 VGPR=32,
//      4.8 GB of weight re-fetch per dispatch). out may alias Al (row-to-row). ----
__global__ __launch_bounds__(256) void combine_bus_kernel(
    const float* __restrict__ h, const float* Al, const float* Ag,
    const float* __restrict__ Wsb, const float* __restrict__ Wl, const float* __restrict__ Wg,
    const float* __restrict__ bias, float* out, int n)
{
    const int lane = threadIdx.x & 63;
    const int wave = blockIdx.x * 4 + (threadIdx.x >> 6);
    const int nW = gridDim.x * 4;
    float wsb[64], wl[64], wg[64];
#pragma unroll
    for (int k = 0; k < 64; ++k) {
        wsb[k] = Wsb[k * 64 + lane];
        wl[k]  = Wl[k * 64 + lane];
        wg[k]  = Wg[k * 64 + lane];
    }
    const float bv = bias[lane];
    for (int row = uni(wave); row < n; row += nW) {
        const float* hr = h + (size_t)row * 64;
        const float* ar = Al + (size_t)row * 64;
        const float* gr = Ag + (size_t)row * 64;
        float a1 = 0.f, a2 = 0.f, a3 = 0.f;
#pragma unroll
        for (int k = 0; k < 64; ++k) {
            a1 += hr[k] * wsb[k];
            a2 += ar[k] * wl[k];
            a3 += gr[k] * wg[k];
        }
        out[(size_t)row * 64 + lane] = fmaxf(a1 + a2 + a3 + bv, 0.f);
    }
}

// ---- gen combine: out = relu(h@Wsg + A@Wm + b). Grid-stride. out may alias A. ----
__global__ __launch_bounds__(256) void combine_gen_kernel(
    const float* __restrict__ h, const float* A,
    const float* __restrict__ Wsg, const float* __restrict__ Wm,
    const float* __restrict__ bias, float* out, int n)
{
    const int lane = threadIdx.x & 63;
    const int wave = blockIdx.x * 4 + (threadIdx.x >> 6);
    const int nW = gridDim.x * 4;
    float ws[64], wm[64];
#pragma unroll
    for (int k = 0; k < 64; ++k) {
        ws[k] = Wsg[k * 64 + lane];
        wm[k] = Wm[k * 64 + lane];
    }
    const float bv = bias[lane];
    for (int row = uni(wave); row < n; row += nW) {
        const float* hr = h + (size_t)row * 64;
        const float* ar = A + (size_t)row * 64;
        float a1 = 0.f, a2 = 0.f;
#pragma unroll
        for (int k = 0; k < 64; ++k) {
            a1 += hr[k] * ws[k];
            a2 += ar[k] * wm[k];
        }
        out[(size_t)row * 64 + lane] = fmaxf(a1 + a2 + bv, 0.f);
    }
}

// ---- column-sum pool ----
__global__ __launch_bounds__(256) void pool_kernel(
    const float* __restrict__ h, int n, float* __restrict__ pool)
{
    int lane = threadIdx.x & 63;
    int w = threadIdx.x >> 6;
    float s = 0.f;
    for (int row = blockIdx.x * 4 + w; row < n; row += gridDim.x * 4)
        s += h[(size_t)row * 64 + lane];
    __shared__ float red[256];
    red[threadIdx.x] = s;
    __syncthreads();
    if (threadIdx.x < 64) {
        float t = red[threadIdx.x] + red[threadIdx.x + 64] + red[threadIdx.x + 128] + red[threadIdx.x + 192];
        atomicAdd(&pool[lane], t);
    }
}

// ---- head: out = relu(g @ Wh + bh) @ Wo + bo ----
__global__ void head_kernel(const float* __restrict__ pool,
                            const float* __restrict__ Wh, const float* __restrict__ bh,
                            const float* __restrict__ Wo, const float* __restrict__ bo,
                            float* __restrict__ out)
{
    __shared__ float g[128];
    __shared__ float hid[64];
    int t = threadIdx.x;  // 128 threads
    g[t] = pool[t];
    __syncthreads();
    if (t < 64) {
        float a = bh[t];
        for (int i = 0; i < 128; ++i) a += g[i] * Wh[i * 64 + t];
        hid[t] = fmaxf(a, 0.f);
    }
    __syncthreads();
    if (t < 16) {
        float a = bo[t];
        for (int j = 0; j < 64; ++j) a += hid[j] * Wo[j * 16 + t];
        out[t] = a;
    }
}

extern "C" void kernel_launch(void* const* d_in, const int* in_sizes, int n_in,
                              void* d_out, int out_size, void* d_ws, size_t ws_size,
                              hipStream_t stream)
{
    const float* x_bus   = (const float*)d_in[0];
    const float* x_gen   = (const float*)d_in[1];
    const int* line_src  = (const int*)d_in[2];
    const int* line_dst  = (const int*)d_in[3];
    const int* g2b_src   = (const int*)d_in[4];
    const int* g2b_dst   = (const int*)d_in[5];
    const int* b2g_src   = (const int*)d_in[6];
    const int* b2g_dst   = (const int*)d_in[7];
    const float* Wsb[2]  = {(const float*)d_in[8],  (const float*)d_in[15]};
    const float* Wsg[2]  = {(const float*)d_in[9],  (const float*)d_in[16]};
    const float* Wl[2]   = {(const float*)d_in[10], (const float*)d_in[17]};
    const float* Wg2b[2] = {(const float*)d_in[11], (const float*)d_in[18]};
    const float* Wb2g[2] = {(const float*)d_in[12], (const float*)d_in[19]};
    const float* bsb[2]  = {(const float*)d_in[13], (const float*)d_in[20]};
    const float* bsg[2]  = {(const float*)d_in[14], (const float*)d_in[21]};
    const float* Wh = (const float*)d_in[22];
    const float* bh = (const float*)d_in[23];
    const float* Wo = (const float*)d_in[24];
    const float* bo = (const float*)d_in[25];
    (void)in_sizes; (void)n_in; (void)out_size; (void)ws_size;

    char* wsB = (char*)d_ws;
    size_t o = 0;
    auto alloc_f = [&](size_t nelem) { float* p = (float*)(wsB + o); o += nelem * sizeof(float); return p; };
    auto alloc_i = [&](size_t nelem) { int*   p = (int*)  (wsB + o); o += nelem * sizeof(int);   return p; };

    float* H1b   = alloc_f((size_t)NB * 64);   // layer-0 bus output
    float* H1g   = alloc_f((size_t)NG * 64);   // layer-0 gen output
    float* Aline = alloc_f((size_t)NB * 64);   // also final hb (layer-1 combine writes here)
    float* Ag2b  = alloc_f((size_t)NB * 64);
    float* Ab2g  = alloc_f((size_t)NG * 64);   // also final hg
    int*   elist = alloc_i(EL + 2 * EX);
    int*   deg   = alloc_i(NSEG);
    int*   off   = alloc_i(NSEG + 1);
    int*   cur   = alloc_i(NSEG);
    int*   part  = alloc_i(256);
    float* pool  = alloc_f(128);

    // ---- CSR build (graph is identical both layers; built once per call) ----
    hipMemsetAsync(deg, 0, NSEG * sizeof(int), stream);
    hipMemsetAsync(pool, 0, 128 * sizeof(float), stream);
    counti_kernel<<<(EL + 255) / 256, 256, 0, stream>>>(line_dst, deg, EL);
    counti_kernel<<<(EX + 255) / 256, 256, 0, stream>>>(g2b_dst, deg + NB, EX);
    counti_kernel<<<(EX + 255) / 256, 256, 0, stream>>>(b2g_dst, deg + 2 * NB, EX);
    scan_part_kernel<<<NTILES, 256, 0, stream>>>(deg, part, NSEG);
    scan_top_kernel<<<1, 256, 0, stream>>>(part, off, NTILES, NSEG);
    scan_write_kernel<<<NTILES, 256, 0, stream>>>(deg, part, off, cur, NSEG);
    fill_kernel<<<(EL + 255) / 256, 256, 0, stream>>>(line_src, line_dst, cur, elist, EL, 0);
    fill_kernel<<<(EX + 255) / 256, 256, 0, stream>>>(g2b_src, g2b_dst, cur, elist, EX, NB);
    fill_kernel<<<(EX + 255) / 256, 256, 0, stream>>>(b2g_src, b2g_dst, cur, elist, EX, 2 * NB);

    const int gbB = (NB + 3) / 4, gbG = (NG + 3) / 4;

    // ---- layer 0 ----
    aggr_bus_kernel<<<gbB, 256, 0, stream>>>(x_bus, x_gen, off, elist, Aline, Ag2b);
    aggr_gen_kernel<<<gbG, 256, 0, stream>>>(x_bus, off, elist, Ab2g);
    combine_bus_kernel<<<1024, 256, 0, stream>>>(x_bus, Aline, Ag2b, Wsb[0], Wl[0], Wg2b[0], bsb[0], H1b, NB);
    combine_gen_kernel<<<512, 256, 0, stream>>>(x_gen, Ab2g, Wsg[0], Wb2g[0], bsg[0], H1g, NG);

    // ---- layer 1 (combine outputs alias A buffers row-to-row) ----
    aggr_bus_kernel<<<gbB, 256, 0, stream>>>(H1b, H1g, off, elist, Aline, Ag2b);
    aggr_gen_kernel<<<gbG, 256, 0, stream>>>(H1b, off, elist, Ab2g);
    combine_bus_kernel<<<1024, 256, 0, stream>>>(H1b, Aline, Ag2b, Wsb[1], Wl[1], Wg2b[1], bsb[1], Aline, NB);
    combine_gen_kernel<<<512, 256, 0, stream>>>(H1g, Ab2g, Wsg[1], Wb2g[1], bsg[1], Ab2g, NG);

    // ---- pool + head ----
    pool_kernel<<<512, 256, 0, stream>>>(Aline, NB, pool);
    pool_kernel<<<512, 256, 0, stream>>>(Ab2g, NG, pool + 64);
    head_kernel<<<1, 128, 0, stream>>>(pool, Wh, bh, Wo, bo, (float*)d_out);
}